// Round 3
// baseline (256.504 us; speedup 1.0000x reference)
//
#include <hip/hip_runtime.h>

#define EPS 1e-6f

typedef short s4v __attribute__((ext_vector_type(4)));
typedef short s8v __attribute__((ext_vector_type(8)));
typedef float f4v __attribute__((ext_vector_type(4)));

__device__ __forceinline__ unsigned short f2bf(float f) {
    unsigned u = __float_as_uint(f);
    u += 0x7FFFu + ((u >> 16) & 1u);   // RTNE
    return (unsigned short)(u >> 16);
}

// split x ~= hi + lo (both bf16); residual <= 2^-17 |x|
__device__ __forceinline__ void split2(float a, float b, unsigned& h, unsigned& l) {
    unsigned short ha = f2bf(a), hb = f2bf(b);
    float ra = a - __uint_as_float((unsigned)ha << 16);
    float rb = b - __uint_as_float((unsigned)hb << 16);
    h = (unsigned)ha | ((unsigned)hb << 16);
    l = (unsigned)f2bf(ra) | ((unsigned)f2bf(rb) << 16);
}

__device__ __forceinline__ s8v ld8(const unsigned short* p) {
    s4v lo = *(const s4v*)p;        // ds_read_b64
    s4v hi = *(const s4v*)(p + 4);  // ds_read_b64
    return __builtin_shufflevector(lo, hi, 0, 1, 2, 3, 4, 5, 6, 7);
}

__device__ __forceinline__ double shfl_xor_dbl(double x, int m) {
    long long l = __double_as_longlong(x);
    int lo = (int)(l & 0xffffffffll), hi = (int)(l >> 32);
    lo = __shfl_xor(lo, m, 64);
    hi = __shfl_xor(hi, m, 64);
    return __longlong_as_double(((long long)hi << 32) | (unsigned)lo);
}

#define P1S 132  // 66 dwords: d*66 mod 32 = 2d, 8B aligned rows

// ---------------- Phase 1: partial M (split-bf16 MFMA) + partial z (fp64) ----------------
// grid (8 chunks, 64 heads), 256 threads. chunk = 512 s-rows, 4 LDS stages of 128.
__global__ __launch_bounds__(256) void mm_phase1(const float* __restrict__ Kg,
                                                 const float* __restrict__ Vg,
                                                 float* __restrict__ partM,
                                                 double* __restrict__ partZ) {
    __shared__ __align__(16) unsigned short Kh[64][P1S], Kl[64][P1S];
    __shared__ __align__(16) unsigned short Vh[64][P1S], Vl[64][P1S];
    __shared__ double zs[256][4];

    const int chunk = blockIdx.x;
    const int head  = blockIdx.y;
    const int t = threadIdx.x;
    const int lane = t & 63;
    const int w = t >> 6;
    const int dg = (t & 15) * 4;       // d-column group
    const int sg = (t >> 4) * 4;       // s-row group (0..60)
    const int m = lane & 15, q = lane >> 4;

    const long hbase = (long)head * 4096 * 64;
    const int srow0 = chunk * 512;

    f4v acc[4];
#pragma unroll
    for (int i = 0; i < 4; ++i) acc[i] = (f4v){0.f, 0.f, 0.f, 0.f};
    double z4[4] = {0.0, 0.0, 0.0, 0.0};

    for (int st = 0; st < 4; ++st) {
        __syncthreads();
        const int sbase = srow0 + st * 128;
#pragma unroll
        for (int half = 0; half < 2; ++half) {
            const int s0 = sg + half * 64;
            float4 r[4];
            // ---- K tile ----
#pragma unroll
            for (int i = 0; i < 4; ++i)
                r[i] = *(const float4*)(Kg + hbase + (long)(sbase + s0 + i) * 64 + dg);
#pragma unroll
            for (int i = 0; i < 4; ++i) {
                z4[0] += (double)r[i].x; z4[1] += (double)r[i].y;
                z4[2] += (double)r[i].z; z4[3] += (double)r[i].w;
            }
#pragma unroll
            for (int j = 0; j < 4; ++j) {
                uint2 ph, pl;
                split2((&r[0].x)[j], (&r[1].x)[j], ph.x, pl.x);
                split2((&r[2].x)[j], (&r[3].x)[j], ph.y, pl.y);
                *(uint2*)&Kh[dg + j][s0] = ph;
                *(uint2*)&Kl[dg + j][s0] = pl;
            }
            // ---- V tile ----
#pragma unroll
            for (int i = 0; i < 4; ++i)
                r[i] = *(const float4*)(Vg + hbase + (long)(sbase + s0 + i) * 64 + dg);
#pragma unroll
            for (int j = 0; j < 4; ++j) {
                uint2 ph, pl;
                split2((&r[0].x)[j], (&r[1].x)[j], ph.x, pl.x);
                split2((&r[2].x)[j], (&r[3].x)[j], ph.y, pl.y);
                *(uint2*)&Vh[dg + j][s0] = ph;
                *(uint2*)&Vl[dg + j][s0] = pl;
            }
        }
        __syncthreads();
        // ---- MFMA: wave w owns M rows [w*16, w*16+16), all 64 cols ----
#pragma unroll
        for (int ks = 0; ks < 4; ++ks) {
            const int k0 = ks * 32 + q * 8;
            s8v ah = ld8(&Kh[w * 16 + m][k0]);
            s8v al = ld8(&Kl[w * 16 + m][k0]);
#pragma unroll
            for (int ct = 0; ct < 4; ++ct) {
                s8v bh = ld8(&Vh[ct * 16 + m][k0]);
                s8v bl = ld8(&Vl[ct * 16 + m][k0]);
                acc[ct] = __builtin_amdgcn_mfma_f32_16x16x32_bf16(ah, bh, acc[ct], 0, 0, 0);
                acc[ct] = __builtin_amdgcn_mfma_f32_16x16x32_bf16(ah, bl, acc[ct], 0, 0, 0);
                acc[ct] = __builtin_amdgcn_mfma_f32_16x16x32_bf16(al, bh, acc[ct], 0, 0, 0);
            }
        }
    }

    // write partial M (C layout: col=lane&15, row=(lane>>4)*4+reg)
    float* pm = partM + ((long)(head * 8 + chunk) << 12);
#pragma unroll
    for (int ct = 0; ct < 4; ++ct)
#pragma unroll
        for (int r2 = 0; r2 < 4; ++r2)
            pm[(w * 16 + q * 4 + r2) * 64 + ct * 16 + m] = acc[ct][r2];

    // reduce z partials
    zs[t][0] = z4[0]; zs[t][1] = z4[1]; zs[t][2] = z4[2]; zs[t][3] = z4[3];
    __syncthreads();
    if (t < 64) {
        double s = 0.0;
#pragma unroll
        for (int g = 0; g < 16; ++g) s += zs[g * 16 + (t >> 2)][t & 3];
        partZ[(head * 8 + chunk) * 64 + t] = s;
    }
}

// ---------------- Reduce: sum chunks -> Mt fp32 (transposed) + z fp64 ----------------
__global__ __launch_bounds__(256) void mm_reduce(const float* __restrict__ partM,
                                                 const double* __restrict__ partZ,
                                                 float* __restrict__ MtG,
                                                 double* __restrict__ zf) {
    __shared__ float Ml[64 * 66];   // [k][n], stride 66 to break bank aliasing
    const int h = blockIdx.x, t = threadIdx.x;
#pragma unroll
    for (int e = 0; e < 16; ++e) {
        const int f = e * 256 + t;
        float s = 0.f;
#pragma unroll
        for (int c = 0; c < 8; ++c) s += partM[(long)(h * 8 + c) * 4096 + f];
        Ml[(f >> 6) * 66 + (f & 63)] = s;
    }
    if (t < 64) {
        double s = 0.0;
#pragma unroll
        for (int c = 0; c < 8; ++c) s += partZ[(h * 8 + c) * 64 + t];
        zf[h * 64 + t] = s;
    }
    __syncthreads();
    // Mt[n][k] = M[k][n], fp32, coalesced 16B stores
#pragma unroll
    for (int i = 0; i < 2; ++i) {
        const int c8 = t + i * 256;           // 0..511, chunk of 8 elems
        const int n = c8 >> 3, k0 = (c8 & 7) * 8;
        float4 o0, o1;
#pragma unroll
        for (int j = 0; j < 4; ++j) (&o0.x)[j] = Ml[(k0 + j) * 66 + n];
#pragma unroll
        for (int j = 0; j < 4; ++j) (&o1.x)[j] = Ml[(k0 + 4 + j) * 66 + n];
        *(float4*)(MtG + (long)h * 4096 + n * 64 + k0) = o0;
        *(float4*)(MtG + (long)h * 4096 + n * 64 + k0 + 4) = o1;
    }
}

#define P2S 68   // 34 dwords: row*34 mod 32 = 2*row, 8B-aligned rows

// ---------------- Phase 2: out = (Q @ M) / (fp32 den) ----------------
// grid (32 s-blocks, 64 heads), 256 threads, 128 rows/block.
__global__ __launch_bounds__(256) void mm_phase2(const float* __restrict__ Qg,
                                                 const float* __restrict__ MtG,
                                                 const double* __restrict__ zf,
                                                 float* __restrict__ outg) {
    __shared__ __align__(16) unsigned short Qh[128][P2S], Ql[128][P2S];
    __shared__ __align__(16) unsigned short Mth[64][P2S], Mtl[64][P2S];
    __shared__ float zl[64];
    __shared__ float denS[128];

    const int sb = blockIdx.x, h = blockIdx.y;
    const int t = threadIdx.x, lane = t & 63, w = t >> 6;
    const long hq = (long)h * 4096 * 64;
    const int s0 = sb * 128;

    {   // stage Mt (fp32 -> split bf16 hi/lo) + z (fp32, matching ref's fp32 z values)
        const float* Msrc = MtG + (long)h * 4096;
        const int n = t >> 2, k0 = (t & 3) * 16;
#pragma unroll
        for (int i = 0; i < 4; ++i) {
            float4 v = *(const float4*)(Msrc + n * 64 + k0 + 4 * i);
            uint2 ph, pl;
            split2(v.x, v.y, ph.x, pl.x);
            split2(v.z, v.w, ph.y, pl.y);
            *(uint2*)&Mth[n][k0 + 4 * i] = ph;
            *(uint2*)&Mtl[n][k0 + 4 * i] = pl;
        }
        if (t < 64) zl[t] = (float)zf[h * 64 + t];
    }
    __syncthreads();

    {   // den: fp32-ROUNDED products (no FMA) summed exactly in fp64, then fp32 + EPS.
        // This replicates the order-independent bulk of the np reference's fp32 dot noise.
        const int half = lane >> 5;
        const int c2 = (lane & 31) * 2;
        for (int it = 0; it < 16; ++it) {
            const int r = it * 8 + w * 2 + half;
            const float2 qv = *(const float2*)(Qg + hq + (long)(s0 + r) * 64 + c2);
            const float t0 = __fmul_rn(qv.x, zl[c2]);
            const float t1 = __fmul_rn(qv.y, zl[c2 + 1]);
            double dp = (double)t0 + (double)t1;
            dp += shfl_xor_dbl(dp, 1);
            dp += shfl_xor_dbl(dp, 2);
            dp += shfl_xor_dbl(dp, 4);
            dp += shfl_xor_dbl(dp, 8);
            dp += shfl_xor_dbl(dp, 16);
            if ((lane & 31) == 0) denS[r] = __fadd_rn((float)dp, EPS);
            unsigned ph, pl;
            split2(qv.x, qv.y, ph, pl);
            *(unsigned*)&Qh[r][c2] = ph;
            *(unsigned*)&Ql[r][c2] = pl;
        }
    }
    __syncthreads();

    const int m = lane & 15, q = lane >> 4;
    s8v b0h[4], b0l[4], b1h[4], b1l[4];
#pragma unroll
    for (int ct = 0; ct < 4; ++ct) {
        b0h[ct] = ld8(&Mth[ct * 16 + m][q * 8]);
        b0l[ct] = ld8(&Mtl[ct * 16 + m][q * 8]);
        b1h[ct] = ld8(&Mth[ct * 16 + m][32 + q * 8]);
        b1l[ct] = ld8(&Mtl[ct * 16 + m][32 + q * 8]);
    }
#pragma unroll
    for (int rt = 0; rt < 2; ++rt) {
        const int sr = w * 32 + rt * 16;
        const s8v a0h = ld8(&Qh[sr + m][q * 8]);
        const s8v a0l = ld8(&Ql[sr + m][q * 8]);
        const s8v a1h = ld8(&Qh[sr + m][32 + q * 8]);
        const s8v a1l = ld8(&Ql[sr + m][32 + q * 8]);
        f4v acc[4];
#pragma unroll
        for (int ct = 0; ct < 4; ++ct) {
            acc[ct] = (f4v){0.f, 0.f, 0.f, 0.f};
            acc[ct] = __builtin_amdgcn_mfma_f32_16x16x32_bf16(a0h, b0h[ct], acc[ct], 0, 0, 0);
            acc[ct] = __builtin_amdgcn_mfma_f32_16x16x32_bf16(a0h, b0l[ct], acc[ct], 0, 0, 0);
            acc[ct] = __builtin_amdgcn_mfma_f32_16x16x32_bf16(a0l, b0h[ct], acc[ct], 0, 0, 0);
            acc[ct] = __builtin_amdgcn_mfma_f32_16x16x32_bf16(a1h, b1h[ct], acc[ct], 0, 0, 0);
            acc[ct] = __builtin_amdgcn_mfma_f32_16x16x32_bf16(a1h, b1l[ct], acc[ct], 0, 0, 0);
            acc[ct] = __builtin_amdgcn_mfma_f32_16x16x32_bf16(a1l, b1h[ct], acc[ct], 0, 0, 0);
        }
#pragma unroll
        for (int ct = 0; ct < 4; ++ct)
#pragma unroll
            for (int r2 = 0; r2 < 4; ++r2) {
                const int rl = sr + q * 4 + r2;
                outg[hq + (long)(s0 + rl) * 64 + ct * 16 + m] =
                    __fdiv_rn(acc[ct][r2], denS[rl]);   // IEEE fp32 divide, like np
            }
    }
}

extern "C" void kernel_launch(void* const* d_in, const int* in_sizes, int n_in,
                              void* d_out, int out_size, void* d_ws, size_t ws_size,
                              hipStream_t stream) {
    const float* K = (const float*)d_in[0];
    const float* V = (const float*)d_in[1];
    const float* Q = (const float*)d_in[2];
    float* out = (float*)d_out;

    char* ws = (char*)d_ws;
    float*  partM = (float*)ws;                      // 64*8*4096*4 = 8 MiB
    double* partZ = (double*)(ws + 8388608);         // 64*8*64*8   = 256 KiB
    float*  MtG   = (float*)(ws + 8650752);          // 64*4096*4   = 1 MiB
    double* zfin  = (double*)(ws + 9699328);         // 64*64*8     = 32 KiB

    mm_phase1<<<dim3(8, 64), 256, 0, stream>>>(K, V, partM, partZ);
    mm_reduce<<<64, 256, 0, stream>>>(partM, partZ, MtG, zfin);
    mm_phase2<<<dim3(32, 64), 256, 0, stream>>>(Q, MtG, zfin, out);
}

// Round 4
// 235.026 us; speedup vs baseline: 1.0914x; 1.0914x over previous
//
#include <hip/hip_runtime.h>

#define EPS 1e-6f

typedef short s4v __attribute__((ext_vector_type(4)));
typedef short s8v __attribute__((ext_vector_type(8)));
typedef float f4v __attribute__((ext_vector_type(4)));

__device__ __forceinline__ unsigned short f2bf(float f) {
    unsigned u = __float_as_uint(f);
    u += 0x7FFFu + ((u >> 16) & 1u);   // RTNE
    return (unsigned short)(u >> 16);
}

// split x ~= hi + lo (both bf16); residual <= 2^-17 |x|
__device__ __forceinline__ void split2(float a, float b, unsigned& h, unsigned& l) {
    unsigned short ha = f2bf(a), hb = f2bf(b);
    float ra = a - __uint_as_float((unsigned)ha << 16);
    float rb = b - __uint_as_float((unsigned)hb << 16);
    h = (unsigned)ha | ((unsigned)hb << 16);
    l = (unsigned)f2bf(ra) | ((unsigned)f2bf(rb) << 16);
}

__device__ __forceinline__ s8v ld8(const unsigned short* p) {
    s4v lo = *(const s4v*)p;        // ds_read_b64
    s4v hi = *(const s4v*)(p + 4);  // ds_read_b64
    return __builtin_shufflevector(lo, hi, 0, 1, 2, 3, 4, 5, 6, 7);
}

__device__ __forceinline__ double shfl_xor_dbl(double x, int m) {
    long long l = __double_as_longlong(x);
    int lo = (int)(l & 0xffffffffll), hi = (int)(l >> 32);
    lo = __shfl_xor(lo, m, 64);
    hi = __shfl_xor(hi, m, 64);
    return __longlong_as_double(((long long)hi << 32) | (unsigned)lo);
}

#define P1S 132  // 66 dwords row stride

// ---------------- Phase 1: partial M (split-bf16 MFMA) + partial z (fp64) ----------------
// grid (8 chunks, 64 heads), 256 threads. chunk = 512 s-rows, 4 LDS stages of 128.
// Software-pipelined: stage st+1's global loads issue before stage st's MFMA barrier.
__global__ __launch_bounds__(256) void mm_phase1(const float* __restrict__ Kg,
                                                 const float* __restrict__ Vg,
                                                 float* __restrict__ partM,
                                                 double* __restrict__ partZ) {
    __shared__ __align__(16) unsigned short Kh[64][P1S], Kl[64][P1S];
    __shared__ __align__(16) unsigned short Vh[64][P1S], Vl[64][P1S];
    __shared__ double zs[256][4];

    const int chunk = blockIdx.x;
    const int head  = blockIdx.y;
    const int t = threadIdx.x;
    const int lane = t & 63;
    const int w = t >> 6;
    const int dg = (t & 15) * 4;       // d-column group
    const int sg = (t >> 4) * 4;       // s-row group (0..60)
    const int m = lane & 15, q = lane >> 4;

    const long hbase = (long)head * 4096 * 64;
    const int srow0 = chunk * 512;

    f4v acc[4];
#pragma unroll
    for (int i = 0; i < 4; ++i) acc[i] = (f4v){0.f, 0.f, 0.f, 0.f};
    double z4[4] = {0.0, 0.0, 0.0, 0.0};

    auto load_stage = [&](int st, float4* kr, float4* vr) {
        const int sbase = srow0 + st * 128;
#pragma unroll
        for (int half = 0; half < 2; ++half)
#pragma unroll
            for (int i = 0; i < 4; ++i) {
                const long off = hbase + (long)(sbase + half * 64 + sg + i) * 64 + dg;
                kr[half * 4 + i] = *(const float4*)(Kg + off);
                vr[half * 4 + i] = *(const float4*)(Vg + off);
            }
    };

    float4 kr[8], vr[8];
    load_stage(0, kr, vr);

#pragma unroll
    for (int st = 0; st < 4; ++st) {
        __syncthreads();   // prev-stage MFMA readers done
        // z accumulation (fp64, per-thread columns dg..dg+3)
#pragma unroll
        for (int i = 0; i < 8; ++i) {
            z4[0] += (double)kr[i].x; z4[1] += (double)kr[i].y;
            z4[2] += (double)kr[i].z; z4[3] += (double)kr[i].w;
        }
        // split + transpose-store to LDS
#pragma unroll
        for (int half = 0; half < 2; ++half) {
            const int s0 = sg + half * 64;
#pragma unroll
            for (int j = 0; j < 4; ++j) {
                uint2 ph, pl;
                split2((&kr[half * 4 + 0].x)[j], (&kr[half * 4 + 1].x)[j], ph.x, pl.x);
                split2((&kr[half * 4 + 2].x)[j], (&kr[half * 4 + 3].x)[j], ph.y, pl.y);
                *(uint2*)&Kh[dg + j][s0] = ph;
                *(uint2*)&Kl[dg + j][s0] = pl;
                split2((&vr[half * 4 + 0].x)[j], (&vr[half * 4 + 1].x)[j], ph.x, pl.x);
                split2((&vr[half * 4 + 2].x)[j], (&vr[half * 4 + 3].x)[j], ph.y, pl.y);
                *(uint2*)&Vh[dg + j][s0] = ph;
                *(uint2*)&Vl[dg + j][s0] = pl;
            }
        }
        // prefetch next stage (overlaps barrier + MFMA below)
        float4 nk[8], nv[8];
        if (st < 3) load_stage(st + 1, nk, nv);
        __syncthreads();
        // MFMA: wave w owns M rows [w*16, w*16+16), all 64 cols
#pragma unroll
        for (int ks = 0; ks < 4; ++ks) {
            const int k0 = ks * 32 + q * 8;
            s8v ah = ld8(&Kh[w * 16 + m][k0]);
            s8v al = ld8(&Kl[w * 16 + m][k0]);
#pragma unroll
            for (int ct = 0; ct < 4; ++ct) {
                s8v bh = ld8(&Vh[ct * 16 + m][k0]);
                s8v bl = ld8(&Vl[ct * 16 + m][k0]);
                acc[ct] = __builtin_amdgcn_mfma_f32_16x16x32_bf16(ah, bh, acc[ct], 0, 0, 0);
                acc[ct] = __builtin_amdgcn_mfma_f32_16x16x32_bf16(ah, bl, acc[ct], 0, 0, 0);
                acc[ct] = __builtin_amdgcn_mfma_f32_16x16x32_bf16(al, bh, acc[ct], 0, 0, 0);
            }
        }
        if (st < 3) {
#pragma unroll
            for (int i = 0; i < 8; ++i) { kr[i] = nk[i]; vr[i] = nv[i]; }
        }
    }

    // write partial M (C layout: col=lane&15, row=(lane>>4)*4+reg)
    float* pm = partM + ((long)(head * 8 + chunk) << 12);
#pragma unroll
    for (int ct = 0; ct < 4; ++ct)
#pragma unroll
        for (int r2 = 0; r2 < 4; ++r2)
            pm[(w * 16 + q * 4 + r2) * 64 + ct * 16 + m] = acc[ct][r2];

    // reduce z partials
    zs[t][0] = z4[0]; zs[t][1] = z4[1]; zs[t][2] = z4[2]; zs[t][3] = z4[3];
    __syncthreads();
    if (t < 64) {
        double s = 0.0;
#pragma unroll
        for (int g = 0; g < 16; ++g) s += zs[g * 16 + (t >> 2)][t & 3];
        partZ[(head * 8 + chunk) * 64 + t] = s;
    }
}

// ---------------- Reduce: sum chunks -> Mt fp32 (transposed) + z fp64 ----------------
// grid (4 k-slices, 64 heads): each block handles 16 of the 64 k-rows of one head.
__global__ __launch_bounds__(256) void mm_reduce(const float* __restrict__ partM,
                                                 const double* __restrict__ partZ,
                                                 float* __restrict__ MtG,
                                                 double* __restrict__ zf) {
    __shared__ float Ml[16][68];
    const int b = blockIdx.x, h = blockIdx.y, t = threadIdx.x;
#pragma unroll
    for (int it = 0; it < 4; ++it) {
        const int fl = it * 256 + t;          // 0..1023 within slice
        const int f = b * 1024 + fl;
        float s = 0.f;
#pragma unroll
        for (int c = 0; c < 8; ++c) s += partM[(long)(h * 8 + c) * 4096 + f];
        Ml[fl >> 6][fl & 63] = s;
    }
    if (b == 0 && t < 64) {
        double s = 0.0;
#pragma unroll
        for (int c = 0; c < 8; ++c) s += partZ[(h * 8 + c) * 64 + t];
        zf[h * 64 + t] = s;
    }
    __syncthreads();
    // Mt[n][k] = M[k][n]: thread t writes row n=t>>2, k-cols b*16 + (t&3)*4 .. +4
    const int n = t >> 2, kq = (t & 3) * 4;
    float4 o;
#pragma unroll
    for (int j = 0; j < 4; ++j) (&o.x)[j] = Ml[kq + j][n];
    *(float4*)(MtG + (long)h * 4096 + n * 64 + b * 16 + kq) = o;
}

#define P2S 68   // 34 dwords row stride

// ---------------- Phase 2: out = (Q @ M) / (fp32 den) ----------------
// grid (32 s-blocks, 64 heads), 256 threads, 128 rows/block.
// A-fragments direct from global (no Q LDS); den via cache-hot half-row re-read.
__global__ __launch_bounds__(256) void mm_phase2(const float* __restrict__ Qg,
                                                 const float* __restrict__ MtG,
                                                 const double* __restrict__ zf,
                                                 float* __restrict__ outg) {
    __shared__ __align__(16) unsigned short Mth[64][P2S], Mtl[64][P2S];
    __shared__ float zl[64];
    __shared__ float denS[128];

    const int sb = blockIdx.x, h = blockIdx.y;
    const int t = threadIdx.x, lane = t & 63, w = t >> 6;
    const long hq = (long)h * 4096 * 64;
    const int s0 = sb * 128;
    const int m = lane & 15, q = lane >> 4;

    // ---- A-fragment loads first: pull the Q tile from HBM early ----
    // qa[0..1]=row0 k0..31, qa[2..3]=row0 k32..63, qa[4..7]=row1 (rt=1)
    float4 qa[8];
    {
        const float* qr0 = Qg + hq + (long)(s0 + w * 32 + m) * 64;
        const float* qr1 = qr0 + 16 * 64;
#pragma unroll
        for (int i = 0; i < 2; ++i) {
            qa[0 + i] = *(const float4*)(qr0 + q * 8 + 4 * i);
            qa[2 + i] = *(const float4*)(qr0 + 32 + q * 8 + 4 * i);
            qa[4 + i] = *(const float4*)(qr1 + q * 8 + 4 * i);
            qa[6 + i] = *(const float4*)(qr1 + 32 + q * 8 + 4 * i);
        }
    }

    // ---- stage Mt (fp32 -> split bf16 hi/lo) + z (fp32) ----
    {
        const float* Msrc = MtG + (long)h * 4096;
        const int n = t >> 2, k0 = (t & 3) * 16;
#pragma unroll
        for (int i = 0; i < 4; ++i) {
            float4 v = *(const float4*)(Msrc + n * 64 + k0 + 4 * i);
            uint2 ph, pl;
            split2(v.x, v.y, ph.x, pl.x);
            split2(v.z, v.w, ph.y, pl.y);
            *(uint2*)&Mth[n][k0 + 4 * i] = ph;
            *(uint2*)&Mtl[n][k0 + 4 * i] = pl;
        }
        if (t < 64) zl[t] = (float)zf[h * 64 + t];
    }
    __syncthreads();

    // ---- den: half-row per thread, L1/L2-hot re-read of Q.
    // fp32-rounded products (no FMA), exact fp64 sum, then fp32 + EPS — same
    // numerics as R3 (replicates the order-independent part of np's fp32 dot).
    {
        const int r = t >> 1, hf = t & 1;
        const float* p = Qg + hq + (long)(s0 + r) * 64 + hf * 32;
        double dp = 0.0;
#pragma unroll
        for (int i = 0; i < 8; ++i) {
            float4 v = *(const float4*)(p + 4 * i);
            dp += (double)__fmul_rn(v.x, zl[hf * 32 + 4 * i + 0]);
            dp += (double)__fmul_rn(v.y, zl[hf * 32 + 4 * i + 1]);
            dp += (double)__fmul_rn(v.z, zl[hf * 32 + 4 * i + 2]);
            dp += (double)__fmul_rn(v.w, zl[hf * 32 + 4 * i + 3]);
        }
        dp += shfl_xor_dbl(dp, 1);
        if (hf == 0) denS[r] = __fadd_rn((float)dp, EPS);
    }

    // ---- B fragments from LDS ----
    s8v b0h[4], b0l[4], b1h[4], b1l[4];
#pragma unroll
    for (int ct = 0; ct < 4; ++ct) {
        b0h[ct] = ld8(&Mth[ct * 16 + m][q * 8]);
        b0l[ct] = ld8(&Mtl[ct * 16 + m][q * 8]);
        b1h[ct] = ld8(&Mth[ct * 16 + m][32 + q * 8]);
        b1l[ct] = ld8(&Mtl[ct * 16 + m][32 + q * 8]);
    }

    union U8 { s8v v; unsigned u[4]; };
    f4v accs[2][4];
#pragma unroll
    for (int rt = 0; rt < 2; ++rt) {
        const float4* qq = &qa[rt * 4];
        U8 a0h, a0l, a1h, a1l;
        split2(qq[0].x, qq[0].y, a0h.u[0], a0l.u[0]);
        split2(qq[0].z, qq[0].w, a0h.u[1], a0l.u[1]);
        split2(qq[1].x, qq[1].y, a0h.u[2], a0l.u[2]);
        split2(qq[1].z, qq[1].w, a0h.u[3], a0l.u[3]);
        split2(qq[2].x, qq[2].y, a1h.u[0], a1l.u[0]);
        split2(qq[2].z, qq[2].w, a1h.u[1], a1l.u[1]);
        split2(qq[3].x, qq[3].y, a1h.u[2], a1l.u[2]);
        split2(qq[3].z, qq[3].w, a1h.u[3], a1l.u[3]);
#pragma unroll
        for (int ct = 0; ct < 4; ++ct) {
            f4v acc = (f4v){0.f, 0.f, 0.f, 0.f};
            acc = __builtin_amdgcn_mfma_f32_16x16x32_bf16(a0h.v, b0h[ct], acc, 0, 0, 0);
            acc = __builtin_amdgcn_mfma_f32_16x16x32_bf16(a0h.v, b0l[ct], acc, 0, 0, 0);
            acc = __builtin_amdgcn_mfma_f32_16x16x32_bf16(a0l.v, b0h[ct], acc, 0, 0, 0);
            acc = __builtin_amdgcn_mfma_f32_16x16x32_bf16(a1h.v, b1h[ct], acc, 0, 0, 0);
            acc = __builtin_amdgcn_mfma_f32_16x16x32_bf16(a1h.v, b1l[ct], acc, 0, 0, 0);
            acc = __builtin_amdgcn_mfma_f32_16x16x32_bf16(a1l.v, b1h[ct], acc, 0, 0, 0);
            accs[rt][ct] = acc;
        }
    }
    __syncthreads();   // denS ready for all waves

#pragma unroll
    for (int rt = 0; rt < 2; ++rt) {
        const int sr = w * 32 + rt * 16;
#pragma unroll
        for (int ct = 0; ct < 4; ++ct)
#pragma unroll
            for (int r2 = 0; r2 < 4; ++r2) {
                const int rl = sr + q * 4 + r2;
                outg[hq + (long)(s0 + rl) * 64 + ct * 16 + m] =
                    __fdiv_rn(accs[rt][ct][r2], denS[rl]);   // IEEE fp32 divide
            }
    }
}

extern "C" void kernel_launch(void* const* d_in, const int* in_sizes, int n_in,
                              void* d_out, int out_size, void* d_ws, size_t ws_size,
                              hipStream_t stream) {
    const float* K = (const float*)d_in[0];
    const float* V = (const float*)d_in[1];
    const float* Q = (const float*)d_in[2];
    float* out = (float*)d_out;

    char* ws = (char*)d_ws;
    float*  partM = (float*)ws;                      // 64*8*4096*4 = 8 MiB
    double* partZ = (double*)(ws + 8388608);         // 64*8*64*8   = 256 KiB
    float*  MtG   = (float*)(ws + 8650752);          // 64*4096*4   = 1 MiB
    double* zfin  = (double*)(ws + 9699328);         // 64*64*8     = 32 KiB

    mm_phase1<<<dim3(8, 64), 256, 0, stream>>>(K, V, partM, partZ);
    mm_reduce<<<dim3(4, 64), 256, 0, stream>>>(partM, partZ, MtG, zfin);
    mm_phase2<<<dim3(32, 64), 256, 0, stream>>>(Q, MtG, zfin, out);
}